// Round 10
// baseline (1244.098 us; speedup 1.0000x reference)
//
#include <hip/hip_runtime.h>
#include <cstdint>
#include <cstddef>

// ---- problem constants ----
#define SEQ_L   4096
#define EMBED   1024
#define HEADS   16
#define WINSZ   128
#define SHIFTSZ 64
#define HD      64
#define NWIN    32
#define MTOT    32768          // B * L
#define ATT_SCALE 0.125f       // HD^-0.5

typedef __bf16 bf16x8 __attribute__((ext_vector_type(8)));
typedef float  f32x4  __attribute__((ext_vector_type(4)));

typedef __attribute__((address_space(3))) void       lds_void;
typedef const __attribute__((address_space(1))) void gbl_void;

// async global->LDS, 16B per lane; LDS dest is wave-uniform base + lane*16
#define GLDS16(g, s) __builtin_amdgcn_global_load_lds((gbl_void*)(g), (lds_void*)(s), 16, 0, 0)

__device__ __forceinline__ unsigned short f2bf(float f) {
    unsigned int u = __float_as_uint(f);
    u += 0x7fffu + ((u >> 16) & 1u);   // round-to-nearest-even
    return (unsigned short)(u >> 16);
}

// ---------------- weight f32 -> bf16 (4 tensors in one launch) ----------------
__launch_bounds__(256)
__global__ void wconv4(const float* __restrict__ s0, const float* __restrict__ s1,
                       const float* __restrict__ s2, const float* __restrict__ s3,
                       unsigned short* __restrict__ d0, unsigned short* __restrict__ d1,
                       unsigned short* __restrict__ d2, unsigned short* __restrict__ d3)
{
    const int b = blockIdx.x;
    const float* s; unsigned short* d; int off;
    if (b < 3072)      { s = s0; d = d0; off = b; }
    else if (b < 4096) { s = s1; d = d1; off = b - 3072; }
    else if (b < 8192) { s = s2; d = d2; off = b - 4096; }
    else               { s = s3; d = d3; off = b - 8192; }
    const int i = (off * 256 + threadIdx.x) * 4;
    const float4 v = *(const float4*)(s + i);
    ushort4 o;
    o.x = f2bf(v.x); o.y = f2bf(v.y); o.z = f2bf(v.z); o.w = f2bf(v.w);
    *(ushort4*)(d + i) = o;
}

// ---------------- LayerNorm, wave-per-row (optionally fused with roll) ----------------
__launch_bounds__(256)
__global__ void ln_kernel(const float* __restrict__ x, const float* __restrict__ gw,
                          const float* __restrict__ gb, unsigned short* __restrict__ out,
                          int shift)
{
    const int row  = blockIdx.x * 4 + (threadIdx.x >> 6);
    const int lane = threadIdx.x & 63;
    const int b    = row >> 12;
    const int lw   = row & 4095;
    const int src  = (b << 12) | ((lw + shift) & 4095);
    const float* xr = x + (size_t)src * EMBED;

    float4 v[4];
    float s = 0.f, q = 0.f;
#pragma unroll
    for (int j = 0; j < 4; ++j) {
        v[j] = ((const float4*)xr)[lane + j * 64];
        s += v[j].x + v[j].y + v[j].z + v[j].w;
        q += v[j].x * v[j].x + v[j].y * v[j].y + v[j].z * v[j].z + v[j].w * v[j].w;
    }
#pragma unroll
    for (int off = 32; off > 0; off >>= 1) {
        s += __shfl_xor(s, off);
        q += __shfl_xor(q, off);
    }
    const float mean = s * (1.0f / 1024.0f);
    const float rstd = rsqrtf(q * (1.0f / 1024.0f) - mean * mean + 1e-5f);

    unsigned short* orow = out + (size_t)row * EMBED;
#pragma unroll
    for (int j = 0; j < 4; ++j) {
        const float4 w4 = ((const float4*)gw)[lane + j * 64];
        const float4 b4 = ((const float4*)gb)[lane + j * 64];
        ushort4 o;
        o.x = f2bf((v[j].x - mean) * rstd * w4.x + b4.x);
        o.y = f2bf((v[j].y - mean) * rstd * w4.y + b4.y);
        o.z = f2bf((v[j].z - mean) * rstd * w4.z + b4.z);
        o.w = f2bf((v[j].w - mean) * rstd * w4.w + b4.w);
        ((ushort4*)orow)[lane + j * 64] = o;
    }
}

// ===== 256x256 GEMM: max-skew pipeline, ONE barrier per K-tile (frozen, R9) =====
__device__ __forceinline__ void stage_half(const unsigned short* __restrict__ g, int ldk,
                                           char* ldsbase, int tid)
{
    const int r  = tid >> 3;                    // 0..63
    const int cg = ((tid & 7) ^ (r & 7)) << 3;  // inverse-swizzled col (elems)
    GLDS16(g + (size_t)r        * ldk + cg, ldsbase + tid * 16);
    GLDS16(g + (size_t)(r + 64) * ldk + cg, ldsbase + 8192 + tid * 16);
}

__device__ __forceinline__ bf16x8 lds_frag(const char* half, int row, int koff)
{
    const int off = koff ^ ((row & 7) << 4);    // st-swizzle on read
    return *(const bf16x8*)(half + row * 128 + off);
}

template<int EPI>
__launch_bounds__(512, 2)
__global__ void gemm256(const unsigned short* __restrict__ A, const unsigned short* __restrict__ W,
                        const float* __restrict__ bias, void* __restrict__ outv,
                        const float* __restrict__ resid, int M, int N, int K)
{
    __shared__ __align__(16) char lds[131072];
    const int tid = threadIdx.x;
    const int l   = tid & 63, w = tid >> 6;
    const int wm  = w >> 2, wn = w & 3;          // 2 x 4 waves
    const int lr  = l & 15, hi = l >> 4;
    const int k0off = hi << 4;
    const int br0   = (wn & 1) << 6;

    int id = blockIdx.x;
    const int nwg = gridDim.x;
    id = (id & 7) * (nwg >> 3) + (id >> 3);
    const int Ntl = N >> 8;
    const int m0  = (id / Ntl) << 8;
    const int n0  = (id % Ntl) << 8;
    const int NT  = K >> 6;

#define HTB(b, ab, h) (lds + ((((b) << 1 | (ab)) << 1 | (h)) << 14))

    stage_half(A + (size_t)m0         * K, K, HTB(0,0,0), tid);
    stage_half(A + (size_t)(m0 + 128) * K, K, HTB(0,0,1), tid);
    stage_half(W + (size_t)n0         * K, K, HTB(0,1,0), tid);
    stage_half(W + (size_t)(n0 + 128) * K, K, HTB(0,1,1), tid);
    asm volatile("s_waitcnt vmcnt(0)" ::: "memory");
    __builtin_amdgcn_s_barrier();

    f32x4 acc[8][4];
#pragma unroll
    for (int f = 0; f < 8; ++f)
#pragma unroll
        for (int n = 0; n < 4; ++n)
            acc[f][n] = (f32x4){0.f, 0.f, 0.f, 0.f};

    bf16x8 bf[4][2], af0[2][2], af1[2][2];

#define LOAD_A_BANK(bank, AHP, F0)                                          \
    af##bank[0][0] = lds_frag(AHP, (F0) * 16 + lr,      k0off);             \
    af##bank[0][1] = lds_frag(AHP, (F0) * 16 + lr,      64 + k0off);        \
    af##bank[1][0] = lds_frag(AHP, (F0) * 16 + 16 + lr, k0off);             \
    af##bank[1][1] = lds_frag(AHP, (F0) * 16 + 16 + lr, 64 + k0off);

#define MFMA_BANK(bank, F0)                                                 \
    __builtin_amdgcn_s_setprio(1);                                          \
    _Pragma("unroll")                                                       \
    for (int n = 0; n < 4; ++n) {                                           \
        acc[F0][n]       = __builtin_amdgcn_mfma_f32_16x16x32_bf16(af##bank[0][0], bf[n][0], acc[F0][n], 0, 0, 0);       \
        acc[F0][n]       = __builtin_amdgcn_mfma_f32_16x16x32_bf16(af##bank[0][1], bf[n][1], acc[F0][n], 0, 0, 0);       \
        acc[(F0) + 1][n] = __builtin_amdgcn_mfma_f32_16x16x32_bf16(af##bank[1][0], bf[n][0], acc[(F0) + 1][n], 0, 0, 0); \
        acc[(F0) + 1][n] = __builtin_amdgcn_mfma_f32_16x16x32_bf16(af##bank[1][1], bf[n][1], acc[(F0) + 1][n], 0, 0, 0); \
    }                                                                       \
    __builtin_amdgcn_s_setprio(0);

#define TILE(BUF)                                                              \
    {                                                                          \
        const char* Ah = HTB(BUF, 0, wm);                                      \
        const char* Bh = HTB(BUF, 1, wn >> 1);                                 \
        _Pragma("unroll")                                                      \
        for (int n = 0; n < 4; ++n) {                                          \
            bf[n][0] = lds_frag(Bh, br0 + n * 16 + lr, k0off);                 \
            bf[n][1] = lds_frag(Bh, br0 + n * 16 + lr, 64 + k0off);            \
        }                                                                      \
        LOAD_A_BANK(0, Ah, 0)                                                  \
        if (t + 1 < NT) {                                                      \
            const unsigned short* An = A + (size_t)m0 * K + (size_t)(t + 1) * 64; \
            const unsigned short* Wn = W + (size_t)n0 * K + (size_t)(t + 1) * 64; \
            stage_half(An,                   K, HTB(BUF ^ 1, 0, 0), tid);      \
            stage_half(An + (size_t)128 * K, K, HTB(BUF ^ 1, 0, 1), tid);      \
            stage_half(Wn,                   K, HTB(BUF ^ 1, 1, 0), tid);      \
            stage_half(Wn + (size_t)128 * K, K, HTB(BUF ^ 1, 1, 1), tid);      \
        }                                                                      \
        LOAD_A_BANK(1, Ah, 2)                                                  \
        asm volatile("s_waitcnt lgkmcnt(4)" ::: "memory");                     \
        MFMA_BANK(0, 0)                                                        \
        LOAD_A_BANK(0, Ah, 4)                                                  \
        asm volatile("s_waitcnt lgkmcnt(4)" ::: "memory");                     \
        MFMA_BANK(1, 2)                                                        \
        LOAD_A_BANK(1, Ah, 6)                                                  \
        asm volatile("s_waitcnt lgkmcnt(4)" ::: "memory");                     \
        MFMA_BANK(0, 4)                                                        \
        asm volatile("s_waitcnt lgkmcnt(0)" ::: "memory");                     \
        MFMA_BANK(1, 6)                                                        \
        asm volatile("s_waitcnt vmcnt(0)" ::: "memory");                       \
        __builtin_amdgcn_s_barrier();                                          \
    }

    int t;
    for (int u = 0; u < (NT >> 1); ++u) {
        t = 2 * u;     TILE(0)
        t = 2 * u + 1; TILE(1)
    }
#undef TILE
#undef LOAD_A_BANK
#undef MFMA_BANK
#undef HTB

    const int cb = n0 + wn * 64;
    float bv[4];
#pragma unroll
    for (int n = 0; n < 4; ++n) bv[n] = bias[cb + n * 16 + lr];

#pragma unroll
    for (int f = 0; f < 8; ++f) {
        const int mbase = m0 + wm * 128 + f * 16 + hi * 4;
#pragma unroll
        for (int n = 0; n < 4; ++n) {
            const int col = cb + n * 16 + lr;
#pragma unroll
            for (int r = 0; r < 4; ++r) {
                const int m = mbase + r;
                float v = acc[f][n][r] + bv[n];
                if constexpr (EPI == 0) {
                    ((unsigned short*)outv)[(size_t)m * N + col] = f2bf(v);
                } else if constexpr (EPI == 1) {
                    const int bb = m >> 12;
                    const int lw = m & 4095;
                    const int ll = (lw + SHIFTSZ) & 4095;
                    const size_t di = ((size_t)(bb << 12) + ll) * (size_t)N + col;
                    ((float*)outv)[di] = resid[di] + v;
                } else if constexpr (EPI == 2) {
                    const float g = 0.5f * v * (1.0f + erff(v * 0.70710678118654752f));
                    ((unsigned short*)outv)[(size_t)m * N + col] = f2bf(g);
                } else {
                    float* o = (float*)outv;
                    const size_t di = (size_t)m * N + col;
                    o[di] = o[di] + v;
                }
            }
        }
    }
}

// ---------------- windowed attention: split-PV, 34.8 KB LDS, 4 blocks/CU ----------------
// Phases: stage K/VT -> QK^T -> [sync] write unnormalized E(j<64) over dead Ks
// -> [sync] PV k=0..63 -> [sync] recompute+write E(j>=64) -> [sync] PV k=64..127
// -> scale by 1/sum (in-register, row->lane mapping identical) -> store.
// E buffer: [128][64] bf16 swizzled (byte ^= (row&7)<<4), exactly 16 KB.
#define SM_VT  16384
#define SM_RPB 33792

__device__ __forceinline__ bf16x8 vt_frag(const char* vt, int d, int kbyte)
{
    const int key = ((d >> 3) & 7) << 4;
    return *(const bf16x8*)(vt + d * 272 + (kbyte ^ key));
}

__launch_bounds__(256, 4)
__global__ void attn_kernel(const unsigned short* __restrict__ qkv, const float* __restrict__ rpb,
                            unsigned short* __restrict__ outp)
{
    __shared__ __align__(16) char smem[34816];

    const int t   = threadIdx.x;
    const int l   = t & 63;
    const int w   = t >> 6;
    const int lr  = l & 15;
    const int lq  = l >> 4;
    const int lk  = lq * 8;
    const int blk = blockIdx.x;
    const int win = blk >> 4;
    const int h   = blk & 15;
    const bool masked = ((win & (NWIN - 1)) == NWIN - 1);

    const unsigned short* qb = qkv + (size_t)(win * WINSZ) * (3 * EMBED) + h * HD;
    const unsigned short* kb = qb + EMBED;
    const unsigned short* vb = qb + 2 * EMBED;
    const int mrow = w * 32;
    float* rpbl = (float*)(smem + SM_RPB);

    // ---- hoist Q fragment loads ----
    bf16x8 aqr[2][2];
#pragma unroll
    for (int ks = 0; ks < 2; ++ks)
#pragma unroll
        for (int mi = 0; mi < 2; ++mi)
            aqr[ks][mi] = *(const bf16x8*)(qb + (size_t)(mrow + mi * 16 + lr) * (3 * EMBED) + ks * 32 + lk);

    if (t < 255) rpbl[t] = rpb[t * HEADS + h];

    // ---- stage K (swizzled-source glds into [0,16K)) ----
    {
        const int c = t & 7;
#pragma unroll
        for (int p = 0; p < 4; ++p) {
            const int r  = (t >> 3) + p * 32;
            const int cg = (c ^ (r & 7)) << 3;
            GLDS16(kb + (size_t)r * (3 * EMBED) + cg, smem + p * 4096 + t * 16);
        }
    }
    // ---- stage V^T ----
    {
        const int c = t & 7;
#pragma unroll
        for (int p = 0; p < 4; ++p) {
            const int k = (t >> 3) + p * 32;
            const uint4 v = *(const uint4*)(vb + (size_t)k * (3 * EMBED) + c * 8);
            const unsigned int vals[4] = {v.x, v.y, v.z, v.w};
            char* base = smem + SM_VT;
#pragma unroll
            for (int e2 = 0; e2 < 4; ++e2) {
                const int d0 = c * 8 + e2 * 2;
                const int key = c << 4;
                *(unsigned short*)(base + d0 * 272 + ((2 * k) ^ key))       = (unsigned short)(vals[e2] & 0xffff);
                *(unsigned short*)(base + (d0 + 1) * 272 + ((2 * k) ^ key)) = (unsigned short)(vals[e2] >> 16);
            }
        }
    }
    asm volatile("s_waitcnt vmcnt(0)" ::: "memory");
    __syncthreads();

    // ---- QK^T ----
    f32x4 sacc[2][8];
#pragma unroll
    for (int a = 0; a < 2; ++a)
#pragma unroll
        for (int b = 0; b < 8; ++b)
            sacc[a][b] = (f32x4){0.f, 0.f, 0.f, 0.f};

#pragma unroll
    for (int ks = 0; ks < 2; ++ks) {
        const int kby = ks * 64 + lq * 16;
        bf16x8 bk8[8];
#pragma unroll
        for (int ni = 0; ni < 8; ++ni)
            bk8[ni] = lds_frag(smem, ni * 16 + lr, kby);
#pragma unroll
        for (int mi = 0; mi < 2; ++mi)
#pragma unroll
            for (int ni = 0; ni < 8; ++ni)
                sacc[mi][ni] = __builtin_amdgcn_mfma_f32_16x16x32_bf16(aqr[ks][mi], bk8[ni], sacc[mi][ni], 0, 0, 0);
    }

    __syncthreads();   // Ks region dead -> E buffer may overlay

    // ---- softmax pass 1: max+sum (all j), write unnormalized E for j<64 ----
    float rsv[2][4], mxv[2][4];
#pragma unroll
    for (int mi = 0; mi < 2; ++mi)
#pragma unroll
        for (int r = 0; r < 4; ++r) {
            const int i = mrow + mi * 16 + lq * 4 + r;
            float v[8];
            float mx = -1e30f;
#pragma unroll
            for (int ni = 0; ni < 8; ++ni) {
                const int j = ni * 16 + lr;
                float sv = sacc[mi][ni][r] * ATT_SCALE + rpbl[j - i + WINSZ - 1];
                if (masked && ((i >= SHIFTSZ) != (j >= SHIFTSZ))) sv -= 100.0f;
                v[ni] = sv;
                mx = fmaxf(mx, sv);
            }
#pragma unroll
            for (int s = 1; s < 16; s <<= 1) mx = fmaxf(mx, __shfl_xor(mx, s));
            float sm = 0.f;
#pragma unroll
            for (int ni = 0; ni < 8; ++ni) {
                const float p = __expf(v[ni] - mx);
                v[ni] = p;
                sm += p;
            }
#pragma unroll
            for (int s = 1; s < 16; s <<= 1) sm += __shfl_xor(sm, s);
            rsv[mi][r] = 1.0f / sm;
            mxv[mi][r] = mx;
            const int key = (i & 7) << 4;
#pragma unroll
            for (int ni = 0; ni < 4; ++ni)
                *(unsigned short*)(smem + i * 128 + ((ni * 32 + lr * 2) ^ key)) = f2bf(v[ni]);
        }

    __syncthreads();

    // ---- PV half 0 (k = 0..63) ----
    f32x4 oacc[2][4];
#pragma unroll
    for (int a = 0; a < 2; ++a)
#pragma unroll
        for (int b = 0; b < 4; ++b)
            oacc[a][b] = (f32x4){0.f, 0.f, 0.f, 0.f};

#pragma unroll
    for (int ksh = 0; ksh < 2; ++ksh) {
        bf16x8 ap[2], av[4];
#pragma unroll
        for (int mi = 0; mi < 2; ++mi) {
            const int ri = mrow + mi * 16 + lr;
            ap[mi] = *(const bf16x8*)(smem + ri * 128 + ((ksh * 64 + lq * 16) ^ ((ri & 7) << 4)));
        }
#pragma unroll
        for (int ni = 0; ni < 4; ++ni)
            av[ni] = vt_frag(smem + SM_VT, ni * 16 + lr, ksh * 64 + lq * 16);
#pragma unroll
        for (int mi = 0; mi < 2; ++mi)
#pragma unroll
            for (int ni = 0; ni < 4; ++ni)
                oacc[mi][ni] = __builtin_amdgcn_mfma_f32_16x16x32_bf16(ap[mi], av[ni], oacc[mi][ni], 0, 0, 0);
    }

    __syncthreads();   // PV half-0 E reads retired

    // ---- softmax pass 2: recompute + write E for j>=64 ----
#pragma unroll
    for (int mi = 0; mi < 2; ++mi)
#pragma unroll
        for (int r = 0; r < 4; ++r) {
            const int i = mrow + mi * 16 + lq * 4 + r;
            const float mx = mxv[mi][r];
            const int key = (i & 7) << 4;
#pragma unroll
            for (int ni = 4; ni < 8; ++ni) {
                const int j = ni * 16 + lr;
                float sv = sacc[mi][ni][r] * ATT_SCALE + rpbl[j - i + WINSZ - 1];
                if (masked && ((i >= SHIFTSZ) != (j >= SHIFTSZ))) sv -= 100.0f;
                *(unsigned short*)(smem + i * 128 + (((ni - 4) * 32 + lr * 2) ^ key)) = f2bf(__expf(sv - mx));
            }
        }

    __syncthreads();

    // ---- PV half 1 (k = 64..127) ----
#pragma unroll
    for (int ksh = 0; ksh < 2; ++ksh) {
        bf16x8 ap[2], av[4];
#pragma unroll
        for (int mi = 0; mi < 2; ++mi) {
            const int ri = mrow + mi * 16 + lr;
            ap[mi] = *(const bf16x8*)(smem + ri * 128 + ((ksh * 64 + lq * 16) ^ ((ri & 7) << 4)));
        }
#pragma unroll
        for (int ni = 0; ni < 4; ++ni)
            av[ni] = vt_frag(smem + SM_VT, ni * 16 + lr, 128 + ksh * 64 + lq * 16);
#pragma unroll
        for (int mi = 0; mi < 2; ++mi)
#pragma unroll
            for (int ni = 0; ni < 4; ++ni)
                oacc[mi][ni] = __builtin_amdgcn_mfma_f32_16x16x32_bf16(ap[mi], av[ni], oacc[mi][ni], 0, 0, 0);
    }

    // ---- scale by 1/sum and store ----
    unsigned short* ob = outp + (size_t)(win * WINSZ) * EMBED + h * HD;
#pragma unroll
    for (int mi = 0; mi < 2; ++mi)
#pragma unroll
        for (int ni = 0; ni < 4; ++ni)
#pragma unroll
            for (int r = 0; r < 4; ++r) {
                const int i = mrow + mi * 16 + lq * 4 + r;
                const int d = ni * 16 + lr;
                ob[(size_t)i * EMBED + d] = f2bf(oacc[mi][ni][r] * rsv[mi][r]);
            }
}

// ---------------- launcher ----------------
extern "C" void kernel_launch(void* const* d_in, const int* in_sizes, int n_in,
                              void* d_out, int out_size, void* d_ws, size_t ws_size,
                              hipStream_t stream)
{
    const float* x      = (const float*)d_in[0];
    const float* qkv_w  = (const float*)d_in[1];
    const float* qkv_b  = (const float*)d_in[2];
    const float* proj_w = (const float*)d_in[3];
    const float* proj_b = (const float*)d_in[4];
    const float* rpb    = (const float*)d_in[5];
    const float* n1w    = (const float*)d_in[6];
    const float* n1b    = (const float*)d_in[7];
    const float* n2w    = (const float*)d_in[8];
    const float* n2b    = (const float*)d_in[9];
    const float* w1     = (const float*)d_in[10];
    const float* b1     = (const float*)d_in[11];
    const float* w2     = (const float*)d_in[12];
    const float* b2     = (const float*)d_in[13];
    float* out = (float*)d_out;

    unsigned short* wqkv  = (unsigned short*)d_ws;                    // 3072*1024
    unsigned short* wproj = wqkv  + (size_t)3072 * 1024;              // 1024*1024
    unsigned short* wm1   = wproj + (size_t)1024 * 1024;              // 4096*1024
    unsigned short* wm2   = wm1   + (size_t)4096 * 1024;              // 4096*1024
    unsigned short* bufA  = wm2   + (size_t)4096 * 1024;              // 32768*1024
    unsigned short* bufB  = bufA  + (size_t)MTOT * EMBED;             // 32768*3072

    // all 4 weight conversions in one launch
    wconv4<<<12288, 256, 0, stream>>>(qkv_w, proj_w, w1, w2, wqkv, wproj, wm1, wm2);

    // h = LN1(x) rolled by -SHIFT
    ln_kernel<<<8192, 256, 0, stream>>>(x, n1w, n1b, bufA, SHIFTSZ);

    // qkv = h @ qkv_w^T + qkv_b   (M=32768, N=3072, K=1024)
    gemm256<0><<<dim3(1536), 512, 0, stream>>>(bufA, wqkv, qkv_b, bufB, nullptr, MTOT, 3 * EMBED, EMBED);

    // windowed attention -> bufA
    attn_kernel<<<4096, 256, 0, stream>>>(bufB, rpb, bufA);

    // x2 = x + roll(attn @ proj_w^T + proj_b, +SHIFT)
    gemm256<1><<<dim3(512), 512, 0, stream>>>(bufA, wproj, proj_b, out, x, MTOT, EMBED, EMBED);

    // h2 = LN2(x2)
    ln_kernel<<<8192, 256, 0, stream>>>(out, n2w, n2b, bufA, 0);

    // MLP chunked (2 x 16384 rows)
    for (int c = 0; c < 2; ++c) {
        const size_t r0 = (size_t)c * 16384;
        gemm256<2><<<dim3(1024), 512, 0, stream>>>(bufA + r0 * EMBED, wm1, b1, bufB, nullptr,
                                                   16384, 4 * EMBED, EMBED);
        gemm256<3><<<dim3(256), 512, 0, stream>>>(bufB, wm2, b2, out + r0 * EMBED, nullptr,
                                                  16384, EMBED, 4 * EMBED);
    }
}

// Round 11
// 1143.694 us; speedup vs baseline: 1.0878x; 1.0878x over previous
//
#include <hip/hip_runtime.h>
#include <hip/hip_fp8.h>
#include <cstdint>
#include <cstddef>

// ---- problem constants ----
#define SEQ_L   4096
#define EMBED   1024
#define HEADS   16
#define WINSZ   128
#define SHIFTSZ 64
#define HD      64
#define NWIN    32
#define MTOT    32768          // B * L
#define ATT_SCALE 0.125f       // HD^-0.5

typedef __bf16 bf16x8 __attribute__((ext_vector_type(8)));
typedef float  f32x4  __attribute__((ext_vector_type(4)));

typedef __attribute__((address_space(3))) void       lds_void;
typedef const __attribute__((address_space(1))) void gbl_void;

// async global->LDS, 16B per lane; LDS dest is wave-uniform base + lane*16
#define GLDS16(g, s) __builtin_amdgcn_global_load_lds((gbl_void*)(g), (lds_void*)(s), 16, 0, 0)

__device__ __forceinline__ unsigned short f2bf(float f) {
    unsigned int u = __float_as_uint(f);
    u += 0x7fffu + ((u >> 16) & 1u);   // round-to-nearest-even
    return (unsigned short)(u >> 16);
}

__device__ __forceinline__ unsigned char f2fp8(float f) {
    __hip_fp8_e4m3 v(f);               // OCP e4m3 (gfx950)
    return (unsigned char)v.__x;
}

__device__ __forceinline__ float bf2f(unsigned short u) {
    return __uint_as_float(((unsigned int)u) << 16);
}

// ---------------- weight f32 -> bf16 (4 tensors in one launch) ----------------
__launch_bounds__(256)
__global__ void wconv4(const float* __restrict__ s0, const float* __restrict__ s1,
                       const float* __restrict__ s2, const float* __restrict__ s3,
                       unsigned short* __restrict__ d0, unsigned short* __restrict__ d1,
                       unsigned short* __restrict__ d2, unsigned short* __restrict__ d3)
{
    const int b = blockIdx.x;
    const float* s; unsigned short* d; int off;
    if (b < 3072)      { s = s0; d = d0; off = b; }
    else if (b < 4096) { s = s1; d = d1; off = b - 3072; }
    else if (b < 8192) { s = s2; d = d2; off = b - 4096; }
    else               { s = s3; d = d3; off = b - 8192; }
    const int i = (off * 256 + threadIdx.x) * 4;
    const float4 v = *(const float4*)(s + i);
    ushort4 o;
    o.x = f2bf(v.x); o.y = f2bf(v.y); o.z = f2bf(v.z); o.w = f2bf(v.w);
    *(ushort4*)(d + i) = o;
}

// ---------------- LayerNorm, wave-per-row (optionally fused with roll) ----------------
__launch_bounds__(256)
__global__ void ln_kernel(const float* __restrict__ x, const float* __restrict__ gw,
                          const float* __restrict__ gb, unsigned short* __restrict__ out,
                          int shift)
{
    const int row  = blockIdx.x * 4 + (threadIdx.x >> 6);
    const int lane = threadIdx.x & 63;
    const int b    = row >> 12;
    const int lw   = row & 4095;
    const int src  = (b << 12) | ((lw + shift) & 4095);
    const float* xr = x + (size_t)src * EMBED;

    float4 v[4];
    float s = 0.f, q = 0.f;
#pragma unroll
    for (int j = 0; j < 4; ++j) {
        v[j] = ((const float4*)xr)[lane + j * 64];
        s += v[j].x + v[j].y + v[j].z + v[j].w;
        q += v[j].x * v[j].x + v[j].y * v[j].y + v[j].z * v[j].z + v[j].w * v[j].w;
    }
#pragma unroll
    for (int off = 32; off > 0; off >>= 1) {
        s += __shfl_xor(s, off);
        q += __shfl_xor(q, off);
    }
    const float mean = s * (1.0f / 1024.0f);
    const float rstd = rsqrtf(q * (1.0f / 1024.0f) - mean * mean + 1e-5f);

    unsigned short* orow = out + (size_t)row * EMBED;
#pragma unroll
    for (int j = 0; j < 4; ++j) {
        const float4 w4 = ((const float4*)gw)[lane + j * 64];
        const float4 b4 = ((const float4*)gb)[lane + j * 64];
        ushort4 o;
        o.x = f2bf((v[j].x - mean) * rstd * w4.x + b4.x);
        o.y = f2bf((v[j].y - mean) * rstd * w4.y + b4.y);
        o.z = f2bf((v[j].z - mean) * rstd * w4.z + b4.z);
        o.w = f2bf((v[j].w - mean) * rstd * w4.w + b4.w);
        ((ushort4*)orow)[lane + j * 64] = o;
    }
}

// ===== 256x256 GEMM: max-skew pipeline, ONE barrier per K-tile (frozen, R9) =====
__device__ __forceinline__ void stage_half(const unsigned short* __restrict__ g, int ldk,
                                           char* ldsbase, int tid)
{
    const int r  = tid >> 3;                    // 0..63
    const int cg = ((tid & 7) ^ (r & 7)) << 3;  // inverse-swizzled col (elems)
    GLDS16(g + (size_t)r        * ldk + cg, ldsbase + tid * 16);
    GLDS16(g + (size_t)(r + 64) * ldk + cg, ldsbase + 8192 + tid * 16);
}

__device__ __forceinline__ bf16x8 lds_frag(const char* half, int row, int koff)
{
    const int off = koff ^ ((row & 7) << 4);    // st-swizzle on read
    return *(const bf16x8*)(half + row * 128 + off);
}

template<int EPI>
__launch_bounds__(512, 2)
__global__ void gemm256(const unsigned short* __restrict__ A, const unsigned short* __restrict__ W,
                        const float* __restrict__ bias, void* __restrict__ outv,
                        const float* __restrict__ resid, int M, int N, int K)
{
    __shared__ __align__(16) char lds[131072];
    const int tid = threadIdx.x;
    const int l   = tid & 63, w = tid >> 6;
    const int wm  = w >> 2, wn = w & 3;          // 2 x 4 waves
    const int lr  = l & 15, hi = l >> 4;
    const int k0off = hi << 4;
    const int br0   = (wn & 1) << 6;

    int id = blockIdx.x;
    const int nwg = gridDim.x;
    id = (id & 7) * (nwg >> 3) + (id >> 3);
    const int Ntl = N >> 8;
    const int m0  = (id / Ntl) << 8;
    const int n0  = (id % Ntl) << 8;
    const int NT  = K >> 6;

#define HTB(b, ab, h) (lds + ((((b) << 1 | (ab)) << 1 | (h)) << 14))

    stage_half(A + (size_t)m0         * K, K, HTB(0,0,0), tid);
    stage_half(A + (size_t)(m0 + 128) * K, K, HTB(0,0,1), tid);
    stage_half(W + (size_t)n0         * K, K, HTB(0,1,0), tid);
    stage_half(W + (size_t)(n0 + 128) * K, K, HTB(0,1,1), tid);
    asm volatile("s_waitcnt vmcnt(0)" ::: "memory");
    __builtin_amdgcn_s_barrier();

    f32x4 acc[8][4];
#pragma unroll
    for (int f = 0; f < 8; ++f)
#pragma unroll
        for (int n = 0; n < 4; ++n)
            acc[f][n] = (f32x4){0.f, 0.f, 0.f, 0.f};

    bf16x8 bf[4][2], af0[2][2], af1[2][2];

#define LOAD_A_BANK(bank, AHP, F0)                                          \
    af##bank[0][0] = lds_frag(AHP, (F0) * 16 + lr,      k0off);             \
    af##bank[0][1] = lds_frag(AHP, (F0) * 16 + lr,      64 + k0off);        \
    af##bank[1][0] = lds_frag(AHP, (F0) * 16 + 16 + lr, k0off);             \
    af##bank[1][1] = lds_frag(AHP, (F0) * 16 + 16 + lr, 64 + k0off);

#define MFMA_BANK(bank, F0)                                                 \
    __builtin_amdgcn_s_setprio(1);                                          \
    _Pragma("unroll")                                                       \
    for (int n = 0; n < 4; ++n) {                                           \
        acc[F0][n]       = __builtin_amdgcn_mfma_f32_16x16x32_bf16(af##bank[0][0], bf[n][0], acc[F0][n], 0, 0, 0);       \
        acc[F0][n]       = __builtin_amdgcn_mfma_f32_16x16x32_bf16(af##bank[0][1], bf[n][1], acc[F0][n], 0, 0, 0);       \
        acc[(F0) + 1][n] = __builtin_amdgcn_mfma_f32_16x16x32_bf16(af##bank[1][0], bf[n][0], acc[(F0) + 1][n], 0, 0, 0); \
        acc[(F0) + 1][n] = __builtin_amdgcn_mfma_f32_16x16x32_bf16(af##bank[1][1], bf[n][1], acc[(F0) + 1][n], 0, 0, 0); \
    }                                                                       \
    __builtin_amdgcn_s_setprio(0);

#define TILE(BUF)                                                              \
    {                                                                          \
        const char* Ah = HTB(BUF, 0, wm);                                      \
        const char* Bh = HTB(BUF, 1, wn >> 1);                                 \
        _Pragma("unroll")                                                      \
        for (int n = 0; n < 4; ++n) {                                          \
            bf[n][0] = lds_frag(Bh, br0 + n * 16 + lr, k0off);                 \
            bf[n][1] = lds_frag(Bh, br0 + n * 16 + lr, 64 + k0off);            \
        }                                                                      \
        LOAD_A_BANK(0, Ah, 0)                                                  \
        if (t + 1 < NT) {                                                      \
            const unsigned short* An = A + (size_t)m0 * K + (size_t)(t + 1) * 64; \
            const unsigned short* Wn = W + (size_t)n0 * K + (size_t)(t + 1) * 64; \
            stage_half(An,                   K, HTB(BUF ^ 1, 0, 0), tid);      \
            stage_half(An + (size_t)128 * K, K, HTB(BUF ^ 1, 0, 1), tid);      \
            stage_half(Wn,                   K, HTB(BUF ^ 1, 1, 0), tid);      \
            stage_half(Wn + (size_t)128 * K, K, HTB(BUF ^ 1, 1, 1), tid);      \
        }                                                                      \
        LOAD_A_BANK(1, Ah, 2)                                                  \
        asm volatile("s_waitcnt lgkmcnt(4)" ::: "memory");                     \
        MFMA_BANK(0, 0)                                                        \
        LOAD_A_BANK(0, Ah, 4)                                                  \
        asm volatile("s_waitcnt lgkmcnt(4)" ::: "memory");                     \
        MFMA_BANK(1, 2)                                                        \
        LOAD_A_BANK(1, Ah, 6)                                                  \
        asm volatile("s_waitcnt lgkmcnt(4)" ::: "memory");                     \
        MFMA_BANK(0, 4)                                                        \
        asm volatile("s_waitcnt lgkmcnt(0)" ::: "memory");                     \
        MFMA_BANK(1, 6)                                                        \
        asm volatile("s_waitcnt vmcnt(0)" ::: "memory");                       \
        __builtin_amdgcn_s_barrier();                                          \
    }

    int t;
    for (int u = 0; u < (NT >> 1); ++u) {
        t = 2 * u;     TILE(0)
        t = 2 * u + 1; TILE(1)
    }
#undef TILE
#undef LOAD_A_BANK
#undef MFMA_BANK
#undef HTB

    const int cb = n0 + wn * 64;
    float bv[4];
#pragma unroll
    for (int n = 0; n < 4; ++n) bv[n] = bias[cb + n * 16 + lr];

#pragma unroll
    for (int f = 0; f < 8; ++f) {
        const int mbase = m0 + wm * 128 + f * 16 + hi * 4;
#pragma unroll
        for (int n = 0; n < 4; ++n) {
            const int col = cb + n * 16 + lr;
#pragma unroll
            for (int r = 0; r < 4; ++r) {
                const int m = mbase + r;
                float v = acc[f][n][r] + bv[n];
                if constexpr (EPI == 0) {
                    ((unsigned short*)outv)[(size_t)m * N + col] = f2bf(v);
                } else if constexpr (EPI == 1) {
                    const int bb = m >> 12;
                    const int lw = m & 4095;
                    const int ll = (lw + SHIFTSZ) & 4095;
                    const size_t di = ((size_t)(bb << 12) + ll) * (size_t)N + col;
                    ((float*)outv)[di] = resid[di] + v;
                } else if constexpr (EPI == 2) {
                    const float g = 0.5f * v * (1.0f + erff(v * 0.70710678118654752f));
                    ((unsigned short*)outv)[(size_t)m * N + col] = f2bf(g);
                } else {
                    float* o = (float*)outv;
                    const size_t di = (size_t)m * N + col;
                    o[di] = o[di] + v;
                }
            }
        }
    }
}

// ---------------- windowed attention: fp8 P/V, ~27 KB LDS, 4 blocks/CU ----------------
// R8 phase structure (stage -> QK^T -> sync -> softmax(writes P) -> sync -> PV),
// but P and V^T stored as fp8 e4m3 and PV uses mfma_f32_16x16x32_fp8_fp8.
// Layout: K bf16 [0,16384) overlaid by P fp8 [128][136] [0,17408)
//         | VT fp8 [64][136] [17408,26112) | rpb f32 [26112,27136).
// Pad-136 rows (34 words) give conflict-free b64 reads (16 lanes -> 16 banks).
#define SM_VT  17408
#define SM_RPB 26112

__launch_bounds__(256, 4)
__global__ void attn_kernel(const unsigned short* __restrict__ qkv, const float* __restrict__ rpb,
                            unsigned short* __restrict__ outp)
{
    __shared__ __align__(16) char smem[27648];

    const int t   = threadIdx.x;
    const int l   = t & 63;
    const int w   = t >> 6;
    const int lr  = l & 15;
    const int lq  = l >> 4;
    const int lk  = lq * 8;
    const int blk = blockIdx.x;
    const int win = blk >> 4;
    const int h   = blk & 15;
    const bool masked = ((win & (NWIN - 1)) == NWIN - 1);

    const unsigned short* qb = qkv + (size_t)(win * WINSZ) * (3 * EMBED) + h * HD;
    const unsigned short* kb = qb + EMBED;
    const unsigned short* vb = qb + 2 * EMBED;
    const int mrow = w * 32;
    float* rpbl = (float*)(smem + SM_RPB);

    // ---- hoist Q fragment loads (latency hides under K/V staging) ----
    bf16x8 aqr[2][2];
#pragma unroll
    for (int ks = 0; ks < 2; ++ks)
#pragma unroll
        for (int mi = 0; mi < 2; ++mi)
            aqr[ks][mi] = *(const bf16x8*)(qb + (size_t)(mrow + mi * 16 + lr) * (3 * EMBED) + ks * 32 + lk);

    if (t < 255) rpbl[t] = rpb[t * HEADS + h];

    // ---- stage K (swizzled-source glds into [0,16K)) ----
    {
        const int c = t & 7;
#pragma unroll
        for (int p = 0; p < 4; ++p) {
            const int r  = (t >> 3) + p * 32;
            const int cg = (c ^ (r & 7)) << 3;
            GLDS16(kb + (size_t)r * (3 * EMBED) + cg, smem + p * 4096 + t * 16);
        }
    }
    // ---- stage V^T as fp8: coalesced bf16 reads, transposed fp8 byte writes ----
    {
        const int c = t & 7;           // d-range c*8 .. c*8+7
#pragma unroll
        for (int p = 0; p < 4; ++p) {
            const int k = (t >> 3) + p * 32;
            const uint4 v = *(const uint4*)(vb + (size_t)k * (3 * EMBED) + c * 8);
            const unsigned int vals[4] = {v.x, v.y, v.z, v.w};
            char* base = smem + SM_VT;
#pragma unroll
            for (int e2 = 0; e2 < 4; ++e2) {
                const int d0 = c * 8 + e2 * 2;
                base[(size_t)d0 * 136 + k]       = (char)f2fp8(bf2f((unsigned short)(vals[e2] & 0xffff)));
                base[(size_t)(d0 + 1) * 136 + k] = (char)f2fp8(bf2f((unsigned short)(vals[e2] >> 16)));
            }
        }
    }
    asm volatile("s_waitcnt vmcnt(0)" ::: "memory");
    __syncthreads();

    // ---- QK^T (bf16, unchanged) ----
    f32x4 sacc[2][8];
#pragma unroll
    for (int a = 0; a < 2; ++a)
#pragma unroll
        for (int b = 0; b < 8; ++b)
            sacc[a][b] = (f32x4){0.f, 0.f, 0.f, 0.f};

#pragma unroll
    for (int ks = 0; ks < 2; ++ks) {
        const int kby = ks * 64 + lq * 16;
        bf16x8 bk8[8];
#pragma unroll
        for (int ni = 0; ni < 8; ++ni)
            bk8[ni] = lds_frag(smem, ni * 16 + lr, kby);
#pragma unroll
        for (int mi = 0; mi < 2; ++mi)
#pragma unroll
            for (int ni = 0; ni < 8; ++ni)
                sacc[mi][ni] = __builtin_amdgcn_mfma_f32_16x16x32_bf16(aqr[ks][mi], bk8[ni], sacc[mi][ni], 0, 0, 0);
    }

    __syncthreads();   // K region dead -> P (fp8) overlays it

    // ---- in-register softmax; write normalized P as fp8 ----
#pragma unroll
    for (int mi = 0; mi < 2; ++mi)
#pragma unroll
        for (int r = 0; r < 4; ++r) {
            const int i = mrow + mi * 16 + lq * 4 + r;
            float v[8];
            float mx = -1e30f;
#pragma unroll
            for (int ni = 0; ni < 8; ++ni) {
                const int j = ni * 16 + lr;
                float sv = sacc[mi][ni][r] * ATT_SCALE + rpbl[j - i + WINSZ - 1];
                if (masked && ((i >= SHIFTSZ) != (j >= SHIFTSZ))) sv -= 100.0f;
                v[ni] = sv;
                mx = fmaxf(mx, sv);
            }
#pragma unroll
            for (int s = 1; s < 16; s <<= 1) mx = fmaxf(mx, __shfl_xor(mx, s));
            float sm = 0.f;
#pragma unroll
            for (int ni = 0; ni < 8; ++ni) {
                const float p = __expf(v[ni] - mx);
                v[ni] = p;
                sm += p;
            }
#pragma unroll
            for (int s = 1; s < 16; s <<= 1) sm += __shfl_xor(sm, s);
            const float rs = 1.0f / sm;
#pragma unroll
            for (int ni = 0; ni < 8; ++ni)
                smem[(size_t)i * 136 + ni * 16 + lr] = (char)f2fp8(v[ni] * rs);
        }

    __syncthreads();

    // ---- PV (fp8 x fp8, K=32 per MFMA, 4 steps) ----
    f32x4 oacc[2][4];
#pragma unroll
    for (int a = 0; a < 2; ++a)
#pragma unroll
        for (int b = 0; b < 4; ++b)
            oacc[a][b] = (f32x4){0.f, 0.f, 0.f, 0.f};

#pragma unroll
    for (int ks = 0; ks < 4; ++ks) {
        const int kb8 = ks * 32 + lq * 8;      // byte == elem offset (fp8)
        long ap[2], av[4];
#pragma unroll
        for (int mi = 0; mi < 2; ++mi)
            ap[mi] = *(const long*)(smem + (size_t)(mrow + mi * 16 + lr) * 136 + kb8);
#pragma unroll
        for (int ni = 0; ni < 4; ++ni)
            av[ni] = *(const long*)(smem + SM_VT + (size_t)(ni * 16 + lr) * 136 + kb8);
#pragma unroll
        for (int mi = 0; mi < 2; ++mi)
#pragma unroll
            for (int ni = 0; ni < 4; ++ni)
                oacc[mi][ni] = __builtin_amdgcn_mfma_f32_16x16x32_fp8_fp8(ap[mi], av[ni], oacc[mi][ni], 0, 0, 0);
    }

    unsigned short* ob = outp + (size_t)(win * WINSZ) * EMBED + h * HD;
#pragma unroll
    for (int mi = 0; mi < 2; ++mi)
#pragma unroll
        for (int ni = 0; ni < 4; ++ni)
#pragma unroll
            for (int r = 0; r < 4; ++r) {
                const int i = mrow + mi * 16 + lq * 4 + r;
                const int d = ni * 16 + lr;
                ob[(size_t)i * EMBED + d] = f2bf(oacc[mi][ni][r]);
            }
}

// ---------------- launcher ----------------
extern "C" void kernel_launch(void* const* d_in, const int* in_sizes, int n_in,
                              void* d_out, int out_size, void* d_ws, size_t ws_size,
                              hipStream_t stream)
{
    const float* x      = (const float*)d_in[0];
    const float* qkv_w  = (const float*)d_in[1];
    const float* qkv_b  = (const float*)d_in[2];
    const float* proj_w = (const float*)d_in[3];
    const float* proj_b = (const float*)d_in[4];
    const float* rpb    = (const float*)d_in[5];
    const float* n1w    = (const float*)d_in[6];
    const float* n1b    = (const float*)d_in[7];
    const float* n2w    = (const float*)d_in[8];
    const float* n2b    = (const float*)d_in[9];
    const float* w1     = (const float*)d_in[10];
    const float* b1     = (const float*)d_in[11];
    const float* w2     = (const float*)d_in[12];
    const float* b2     = (const float*)d_in[13];
    float* out = (float*)d_out;

    unsigned short* wqkv  = (unsigned short*)d_ws;                    // 3072*1024
    unsigned short* wproj = wqkv  + (size_t)3072 * 1024;              // 1024*1024
    unsigned short* wm1   = wproj + (size_t)1024 * 1024;              // 4096*1024
    unsigned short* wm2   = wm1   + (size_t)4096 * 1024;              // 4096*1024
    unsigned short* bufA  = wm2   + (size_t)4096 * 1024;              // 32768*1024
    unsigned short* bufB  = bufA  + (size_t)MTOT * EMBED;             // 32768*3072

    // all 4 weight conversions in one launch
    wconv4<<<12288, 256, 0, stream>>>(qkv_w, proj_w, w1, w2, wqkv, wproj, wm1, wm2);

    // h = LN1(x) rolled by -SHIFT
    ln_kernel<<<8192, 256, 0, stream>>>(x, n1w, n1b, bufA, SHIFTSZ);

    // qkv = h @ qkv_w^T + qkv_b   (M=32768, N=3072, K=1024)
    gemm256<0><<<dim3(1536), 512, 0, stream>>>(bufA, wqkv, qkv_b, bufB, nullptr, MTOT, 3 * EMBED, EMBED);

    // windowed attention -> bufA
    attn_kernel<<<4096, 256, 0, stream>>>(bufB, rpb, bufA);

    // x2 = x + roll(attn @ proj_w^T + proj_b, +SHIFT)
    gemm256<1><<<dim3(512), 512, 0, stream>>>(bufA, wproj, proj_b, out, x, MTOT, EMBED, EMBED);

    // h2 = LN2(x2)
    ln_kernel<<<8192, 256, 0, stream>>>(out, n2w, n2b, bufA, 0);

    // MLP chunked (2 x 16384 rows)
    for (int c = 0; c < 2; ++c) {
        const size_t r0 = (size_t)c * 16384;
        gemm256<2><<<dim3(1024), 512, 0, stream>>>(bufA + r0 * EMBED, wm1, b1, bufB, nullptr,
                                                   16384, 4 * EMBED, EMBED);
        gemm256<3><<<dim3(256), 512, 0, stream>>>(bufB, wm2, b2, out + r0 * EMBED, nullptr,
                                                  16384, EMBED, 4 * EMBED);
    }
}

// Round 12
// 1132.166 us; speedup vs baseline: 1.0989x; 1.0102x over previous
//
#include <hip/hip_runtime.h>
#include <cstdint>
#include <cstddef>

// ---- problem constants ----
#define SEQ_L   4096
#define EMBED   1024
#define HEADS   16
#define WINSZ   128
#define SHIFTSZ 64
#define HD      64
#define NWIN    32
#define MTOT    32768          // B * L
#define ATT_SCALE 0.125f       // HD^-0.5

typedef __bf16 bf16x8 __attribute__((ext_vector_type(8)));
typedef float  f32x4  __attribute__((ext_vector_type(4)));

typedef __attribute__((address_space(3))) void       lds_void;
typedef const __attribute__((address_space(1))) void gbl_void;

// async global->LDS, 16B per lane; LDS dest is wave-uniform base + lane*16
#define GLDS16(g, s) __builtin_amdgcn_global_load_lds((gbl_void*)(g), (lds_void*)(s), 16, 0, 0)

__device__ __forceinline__ unsigned short f2bf(float f) {
    unsigned int u = __float_as_uint(f);
    u += 0x7fffu + ((u >> 16) & 1u);   // round-to-nearest-even
    return (unsigned short)(u >> 16);
}

// ---------------- weight f32 -> bf16 (4 tensors in one launch) ----------------
__launch_bounds__(256)
__global__ void wconv4(const float* __restrict__ s0, const float* __restrict__ s1,
                       const float* __restrict__ s2, const float* __restrict__ s3,
                       unsigned short* __restrict__ d0, unsigned short* __restrict__ d1,
                       unsigned short* __restrict__ d2, unsigned short* __restrict__ d3)
{
    const int b = blockIdx.x;
    const float* s; unsigned short* d; int off;
    if (b < 3072)      { s = s0; d = d0; off = b; }
    else if (b < 4096) { s = s1; d = d1; off = b - 3072; }
    else if (b < 8192) { s = s2; d = d2; off = b - 4096; }
    else               { s = s3; d = d3; off = b - 8192; }
    const int i = (off * 256 + threadIdx.x) * 4;
    const float4 v = *(const float4*)(s + i);
    ushort4 o;
    o.x = f2bf(v.x); o.y = f2bf(v.y); o.z = f2bf(v.z); o.w = f2bf(v.w);
    *(ushort4*)(d + i) = o;
}

// ---------------- LayerNorm, wave-per-row (optionally fused with roll) ----------------
__launch_bounds__(256)
__global__ void ln_kernel(const float* __restrict__ x, const float* __restrict__ gw,
                          const float* __restrict__ gb, unsigned short* __restrict__ out,
                          int shift)
{
    const int row  = blockIdx.x * 4 + (threadIdx.x >> 6);
    const int lane = threadIdx.x & 63;
    const int b    = row >> 12;
    const int lw   = row & 4095;
    const int src  = (b << 12) | ((lw + shift) & 4095);
    const float* xr = x + (size_t)src * EMBED;

    float4 v[4];
    float s = 0.f, q = 0.f;
#pragma unroll
    for (int j = 0; j < 4; ++j) {
        v[j] = ((const float4*)xr)[lane + j * 64];
        s += v[j].x + v[j].y + v[j].z + v[j].w;
        q += v[j].x * v[j].x + v[j].y * v[j].y + v[j].z * v[j].z + v[j].w * v[j].w;
    }
#pragma unroll
    for (int off = 32; off > 0; off >>= 1) {
        s += __shfl_xor(s, off);
        q += __shfl_xor(q, off);
    }
    const float mean = s * (1.0f / 1024.0f);
    const float rstd = rsqrtf(q * (1.0f / 1024.0f) - mean * mean + 1e-5f);

    unsigned short* orow = out + (size_t)row * EMBED;
#pragma unroll
    for (int j = 0; j < 4; ++j) {
        const float4 w4 = ((const float4*)gw)[lane + j * 64];
        const float4 b4 = ((const float4*)gb)[lane + j * 64];
        ushort4 o;
        o.x = f2bf((v[j].x - mean) * rstd * w4.x + b4.x);
        o.y = f2bf((v[j].y - mean) * rstd * w4.y + b4.y);
        o.z = f2bf((v[j].z - mean) * rstd * w4.z + b4.z);
        o.w = f2bf((v[j].w - mean) * rstd * w4.w + b4.w);
        ((ushort4*)orow)[lane + j * 64] = o;
    }
}

// ===== 256x256 GEMM: max-skew pipeline, ONE barrier per K-tile (frozen, R9) =====
__device__ __forceinline__ void stage_half(const unsigned short* __restrict__ g, int ldk,
                                           char* ldsbase, int tid)
{
    const int r  = tid >> 3;                    // 0..63
    const int cg = ((tid & 7) ^ (r & 7)) << 3;  // inverse-swizzled col (elems)
    GLDS16(g + (size_t)r        * ldk + cg, ldsbase + tid * 16);
    GLDS16(g + (size_t)(r + 64) * ldk + cg, ldsbase + 8192 + tid * 16);
}

__device__ __forceinline__ bf16x8 lds_frag(const char* half, int row, int koff)
{
    const int off = koff ^ ((row & 7) << 4);    // st-swizzle on read
    return *(const bf16x8*)(half + row * 128 + off);
}

template<int EPI>
__launch_bounds__(512, 2)
__global__ void gemm256(const unsigned short* __restrict__ A, const unsigned short* __restrict__ W,
                        const float* __restrict__ bias, void* __restrict__ outv,
                        const float* __restrict__ resid, int M, int N, int K)
{
    __shared__ __align__(16) char lds[131072];
    const int tid = threadIdx.x;
    const int l   = tid & 63, w = tid >> 6;
    const int wm  = w >> 2, wn = w & 3;          // 2 x 4 waves
    const int lr  = l & 15, hi = l >> 4;
    const int k0off = hi << 4;
    const int br0   = (wn & 1) << 6;

    int id = blockIdx.x;
    const int nwg = gridDim.x;
    id = (id & 7) * (nwg >> 3) + (id >> 3);
    const int Ntl = N >> 8;
    const int m0  = (id / Ntl) << 8;
    const int n0  = (id % Ntl) << 8;
    const int NT  = K >> 6;

#define HTB(b, ab, h) (lds + ((((b) << 1 | (ab)) << 1 | (h)) << 14))

    stage_half(A + (size_t)m0         * K, K, HTB(0,0,0), tid);
    stage_half(A + (size_t)(m0 + 128) * K, K, HTB(0,0,1), tid);
    stage_half(W + (size_t)n0         * K, K, HTB(0,1,0), tid);
    stage_half(W + (size_t)(n0 + 128) * K, K, HTB(0,1,1), tid);
    asm volatile("s_waitcnt vmcnt(0)" ::: "memory");
    __builtin_amdgcn_s_barrier();

    f32x4 acc[8][4];
#pragma unroll
    for (int f = 0; f < 8; ++f)
#pragma unroll
        for (int n = 0; n < 4; ++n)
            acc[f][n] = (f32x4){0.f, 0.f, 0.f, 0.f};

    bf16x8 bf[4][2], af0[2][2], af1[2][2];

#define LOAD_A_BANK(bank, AHP, F0)                                          \
    af##bank[0][0] = lds_frag(AHP, (F0) * 16 + lr,      k0off);             \
    af##bank[0][1] = lds_frag(AHP, (F0) * 16 + lr,      64 + k0off);        \
    af##bank[1][0] = lds_frag(AHP, (F0) * 16 + 16 + lr, k0off);             \
    af##bank[1][1] = lds_frag(AHP, (F0) * 16 + 16 + lr, 64 + k0off);

#define MFMA_BANK(bank, F0)                                                 \
    __builtin_amdgcn_s_setprio(1);                                          \
    _Pragma("unroll")                                                       \
    for (int n = 0; n < 4; ++n) {                                           \
        acc[F0][n]       = __builtin_amdgcn_mfma_f32_16x16x32_bf16(af##bank[0][0], bf[n][0], acc[F0][n], 0, 0, 0);       \
        acc[F0][n]       = __builtin_amdgcn_mfma_f32_16x16x32_bf16(af##bank[0][1], bf[n][1], acc[F0][n], 0, 0, 0);       \
        acc[(F0) + 1][n] = __builtin_amdgcn_mfma_f32_16x16x32_bf16(af##bank[1][0], bf[n][0], acc[(F0) + 1][n], 0, 0, 0); \
        acc[(F0) + 1][n] = __builtin_amdgcn_mfma_f32_16x16x32_bf16(af##bank[1][1], bf[n][1], acc[(F0) + 1][n], 0, 0, 0); \
    }                                                                       \
    __builtin_amdgcn_s_setprio(0);

#define TILE(BUF)                                                              \
    {                                                                          \
        const char* Ah = HTB(BUF, 0, wm);                                      \
        const char* Bh = HTB(BUF, 1, wn >> 1);                                 \
        _Pragma("unroll")                                                      \
        for (int n = 0; n < 4; ++n) {                                          \
            bf[n][0] = lds_frag(Bh, br0 + n * 16 + lr, k0off);                 \
            bf[n][1] = lds_frag(Bh, br0 + n * 16 + lr, 64 + k0off);            \
        }                                                                      \
        LOAD_A_BANK(0, Ah, 0)                                                  \
        if (t + 1 < NT) {                                                      \
            const unsigned short* An = A + (size_t)m0 * K + (size_t)(t + 1) * 64; \
            const unsigned short* Wn = W + (size_t)n0 * K + (size_t)(t + 1) * 64; \
            stage_half(An,                   K, HTB(BUF ^ 1, 0, 0), tid);      \
            stage_half(An + (size_t)128 * K, K, HTB(BUF ^ 1, 0, 1), tid);      \
            stage_half(Wn,                   K, HTB(BUF ^ 1, 1, 0), tid);      \
            stage_half(Wn + (size_t)128 * K, K, HTB(BUF ^ 1, 1, 1), tid);      \
        }                                                                      \
        LOAD_A_BANK(1, Ah, 2)                                                  \
        asm volatile("s_waitcnt lgkmcnt(4)" ::: "memory");                     \
        MFMA_BANK(0, 0)                                                        \
        LOAD_A_BANK(0, Ah, 4)                                                  \
        asm volatile("s_waitcnt lgkmcnt(4)" ::: "memory");                     \
        MFMA_BANK(1, 2)                                                        \
        LOAD_A_BANK(1, Ah, 6)                                                  \
        asm volatile("s_waitcnt lgkmcnt(4)" ::: "memory");                     \
        MFMA_BANK(0, 4)                                                        \
        asm volatile("s_waitcnt lgkmcnt(0)" ::: "memory");                     \
        MFMA_BANK(1, 6)                                                        \
        asm volatile("s_waitcnt vmcnt(0)" ::: "memory");                       \
        __builtin_amdgcn_s_barrier();                                          \
    }

    int t;
    for (int u = 0; u < (NT >> 1); ++u) {
        t = 2 * u;     TILE(0)
        t = 2 * u + 1; TILE(1)
    }
#undef TILE
#undef LOAD_A_BANK
#undef MFMA_BANK
#undef HTB

    const int cb = n0 + wn * 64;
    float bv[4];
#pragma unroll
    for (int n = 0; n < 4; ++n) bv[n] = bias[cb + n * 16 + lr];

#pragma unroll
    for (int f = 0; f < 8; ++f) {
        const int mbase = m0 + wm * 128 + f * 16 + hi * 4;
#pragma unroll
        for (int n = 0; n < 4; ++n) {
            const int col = cb + n * 16 + lr;
#pragma unroll
            for (int r = 0; r < 4; ++r) {
                const int m = mbase + r;
                float v = acc[f][n][r] + bv[n];
                if constexpr (EPI == 0) {
                    ((unsigned short*)outv)[(size_t)m * N + col] = f2bf(v);
                } else if constexpr (EPI == 1) {
                    const int bb = m >> 12;
                    const int lw = m & 4095;
                    const int ll = (lw + SHIFTSZ) & 4095;
                    const size_t di = ((size_t)(bb << 12) + ll) * (size_t)N + col;
                    ((float*)outv)[di] = resid[di] + v;
                } else if constexpr (EPI == 2) {
                    const float g = 0.5f * v * (1.0f + erff(v * 0.70710678118654752f));
                    ((unsigned short*)outv)[(size_t)m * N + col] = f2bf(g);
                } else {
                    float* o = (float*)outv;
                    const size_t di = (size_t)m * N + col;
                    o[di] = o[di] + v;
                }
            }
        }
    }
}

// ---------------- windowed attention: R8 structure + b32 pair-write V^T staging ----------------
// LDS overlay: P (34 KB bf16) reuses the dead Ks region after QK^T. 52 KB -> 3 blocks/CU.
// V^T staging: each thread covers k-pairs (k0 even, k0+1): packs V[k0][d],V[k0+1][d]
// into one dword -> 16 ds_write_b32 instead of 32 ds_write_b16 (same byte image;
// read side vt_frag unchanged). Alignment: 2*k0 % 4 == 0, key % 16 == 0.
#define SM_VT  34816
#define SM_RPB 52224

__device__ __forceinline__ bf16x8 vt_frag(const char* vt, int d, int kbyte)
{
    const int key = ((d >> 3) & 7) << 4;
    return *(const bf16x8*)(vt + d * 272 + (kbyte ^ key));
}

__launch_bounds__(256, 3)
__global__ void attn_kernel(const unsigned short* __restrict__ qkv, const float* __restrict__ rpb,
                            unsigned short* __restrict__ outp)
{
    __shared__ __align__(16) char smem[53248];

    const int t   = threadIdx.x;
    const int l   = t & 63;
    const int w   = t >> 6;
    const int lr  = l & 15;
    const int lq  = l >> 4;
    const int lk  = lq * 8;
    const int blk = blockIdx.x;
    const int win = blk >> 4;
    const int h   = blk & 15;
    const bool masked = ((win & (NWIN - 1)) == NWIN - 1);

    const unsigned short* qb = qkv + (size_t)(win * WINSZ) * (3 * EMBED) + h * HD;
    const unsigned short* kb = qb + EMBED;
    const unsigned short* vb = qb + 2 * EMBED;
    const int mrow = w * 32;
    float* rpbl = (float*)(smem + SM_RPB);

    // ---- hoist Q fragment loads (latency hides under K/V staging) ----
    bf16x8 aqr[2][2];
#pragma unroll
    for (int ks = 0; ks < 2; ++ks)
#pragma unroll
        for (int mi = 0; mi < 2; ++mi)
            aqr[ks][mi] = *(const bf16x8*)(qb + (size_t)(mrow + mi * 16 + lr) * (3 * EMBED) + ks * 32 + lk);

    if (t < 255) rpbl[t] = rpb[t * HEADS + h];

    // ---- stage K (swizzled-source glds into [0,16K)) ----
    {
        const int c = t & 7;
#pragma unroll
        for (int p = 0; p < 4; ++p) {
            const int r  = (t >> 3) + p * 32;
            const int cg = (c ^ (r & 7)) << 3;
            GLDS16(kb + (size_t)r * (3 * EMBED) + cg, smem + p * 4096 + t * 16);
        }
    }
    // ---- stage V^T: k-pair packing, b32 writes (half the LDS write ops) ----
    {
        const int c  = t & 7;          // d-octet: d = c*8 .. c*8+7
        const int tp = t >> 3;         // 0..31
        char* base = smem + SM_VT;
        const int key = c << 4;
#pragma unroll
        for (int p = 0; p < 2; ++p) {
            const int k0 = 2 * (tp + p * 32);   // even
            const uint4 va = *(const uint4*)(vb + (size_t)k0       * (3 * EMBED) + c * 8);
            const uint4 vc = *(const uint4*)(vb + (size_t)(k0 + 1) * (3 * EMBED) + c * 8);
            const unsigned int ra[4] = {va.x, va.y, va.z, va.w};
            const unsigned int rc[4] = {vc.x, vc.y, vc.z, vc.w};
#pragma unroll
            for (int e2 = 0; e2 < 4; ++e2) {
                const int d0 = c * 8 + e2 * 2;
                const unsigned int w0 = (ra[e2] & 0xffffu) | ((rc[e2] & 0xffffu) << 16);
                const unsigned int w1 = (ra[e2] >> 16)     | (rc[e2] & 0xffff0000u);
                *(unsigned int*)(base + (size_t)d0       * 272 + ((2 * k0) ^ key)) = w0;
                *(unsigned int*)(base + (size_t)(d0 + 1) * 272 + ((2 * k0) ^ key)) = w1;
            }
        }
    }
    asm volatile("s_waitcnt vmcnt(0)" ::: "memory");
    __syncthreads();

    // ---- QK^T ----
    f32x4 sacc[2][8];
#pragma unroll
    for (int a = 0; a < 2; ++a)
#pragma unroll
        for (int b = 0; b < 8; ++b)
            sacc[a][b] = (f32x4){0.f, 0.f, 0.f, 0.f};

#pragma unroll
    for (int ks = 0; ks < 2; ++ks) {
        const int kby = ks * 64 + lq * 16;
        bf16x8 bk8[8];
#pragma unroll
        for (int ni = 0; ni < 8; ++ni)
            bk8[ni] = lds_frag(smem, ni * 16 + lr, kby);
#pragma unroll
        for (int mi = 0; mi < 2; ++mi)
#pragma unroll
            for (int ni = 0; ni < 8; ++ni)
                sacc[mi][ni] = __builtin_amdgcn_mfma_f32_16x16x32_bf16(aqr[ks][mi], bk8[ni], sacc[mi][ni], 0, 0, 0);
    }

    __syncthreads();   // K region dead everywhere -> P may overlay it

    // ---- in-register softmax per row; P -> smem[0..34816) ----
#pragma unroll
    for (int mi = 0; mi < 2; ++mi)
#pragma unroll
        for (int r = 0; r < 4; ++r) {
            const int i = mrow + mi * 16 + lq * 4 + r;
            float v[8];
            float mx = -1e30f;
#pragma unroll
            for (int ni = 0; ni < 8; ++ni) {
                const int j = ni * 16 + lr;
                float sv = sacc[mi][ni][r] * ATT_SCALE + rpbl[j - i + WINSZ - 1];
                if (masked && ((i >= SHIFTSZ) != (j >= SHIFTSZ))) sv -= 100.0f;
                v[ni] = sv;
                mx = fmaxf(mx, sv);
            }
#pragma unroll
            for (int s = 1; s < 16; s <<= 1) mx = fmaxf(mx, __shfl_xor(mx, s));
            float sm = 0.f;
#pragma unroll
            for (int ni = 0; ni < 8; ++ni) {
                const float p = __expf(v[ni] - mx);
                v[ni] = p;
                sm += p;
            }
#pragma unroll
            for (int s = 1; s < 16; s <<= 1) sm += __shfl_xor(sm, s);
            const float rs = 1.0f / sm;
#pragma unroll
            for (int ni = 0; ni < 8; ++ni)
                *(unsigned short*)(smem + ((size_t)i * 136 + ni * 16 + lr) * 2) = f2bf(v[ni] * rs);
        }

    __syncthreads();

    // ---- PV ----
    f32x4 oacc[2][4];
#pragma unroll
    for (int a = 0; a < 2; ++a)
#pragma unroll
        for (int b = 0; b < 4; ++b)
            oacc[a][b] = (f32x4){0.f, 0.f, 0.f, 0.f};

#pragma unroll
    for (int ks = 0; ks < 4; ++ks) {
        const int k0 = ks * 32;
        bf16x8 ap[2], av[4];
#pragma unroll
        for (int mi = 0; mi < 2; ++mi)
            ap[mi] = *(const bf16x8*)(smem + ((size_t)(mrow + mi * 16 + lr) * 136 + k0 + lk) * 2);
#pragma unroll
        for (int ni = 0; ni < 4; ++ni)
            av[ni] = vt_frag(smem + SM_VT, ni * 16 + lr, k0 * 2 + lq * 16);
#pragma unroll
        for (int mi = 0; mi < 2; ++mi)
#pragma unroll
            for (int ni = 0; ni < 4; ++ni)
                oacc[mi][ni] = __builtin_amdgcn_mfma_f32_16x16x32_bf16(ap[mi], av[ni], oacc[mi][ni], 0, 0, 0);
    }

    unsigned short* ob = outp + (size_t)(win * WINSZ) * EMBED + h * HD;
#pragma unroll
    for (int mi = 0; mi < 2; ++mi)
#pragma unroll
        for (int ni = 0; ni < 4; ++ni)
#pragma unroll
            for (int r = 0; r < 4; ++r) {
                const int i = mrow + mi * 16 + lq * 4 + r;
                const int d = ni * 16 + lr;
                ob[(size_t)i * EMBED + d] = f2bf(oacc[mi][ni][r]);
            }
}

// ---------------- launcher ----------------
extern "C" void kernel_launch(void* const* d_in, const int* in_sizes, int n_in,
                              void* d_out, int out_size, void* d_ws, size_t ws_size,
                              hipStream_t stream)
{
    const float* x      = (const float*)d_in[0];
    const float* qkv_w  = (const float*)d_in[1];
    const float* qkv_b  = (const float*)d_in[2];
    const float* proj_w = (const float*)d_in[3];
    const float* proj_b = (const float*)d_in[4];
    const float* rpb    = (const float*)d_in[5];
    const float* n1w    = (const float*)d_in[6];
    const float* n1b    = (const float*)d_in[7];
    const float* n2w    = (const float*)d_in[8];
    const float* n2b    = (const float*)d_in[9];
    const float* w1     = (const float*)d_in[10];
    const float* b1     = (const float*)d_in[11];
    const float* w2     = (const float*)d_in[12];
    const float* b2     = (const float*)d_in[13];
    float* out = (float*)d_out;

    unsigned short* wqkv  = (unsigned short*)d_ws;                    // 3072*1024
    unsigned short* wproj = wqkv  + (size_t)3072 * 1024;              // 1024*1024
    unsigned short* wm1   = wproj + (size_t)1024 * 1024;              // 4096*1024
    unsigned short* wm2   = wm1   + (size_t)4096 * 1024;              // 4096*1024
    unsigned short* bufA  = wm2   + (size_t)4096 * 1024;              // 32768*1024
    unsigned short* bufB  = bufA  + (size_t)MTOT * EMBED;             // 32768*3072

    // all 4 weight conversions in one launch
    wconv4<<<12288, 256, 0, stream>>>(qkv_w, proj_w, w1, w2, wqkv, wproj, wm1, wm2);

    // h = LN1(x) rolled by -SHIFT
    ln_kernel<<<8192, 256, 0, stream>>>(x, n1w, n1b, bufA, SHIFTSZ);

    // qkv = h @ qkv_w^T + qkv_b   (M=32768, N=3072, K=1024)
    gemm256<0><<<dim3(1536), 512, 0, stream>>>(bufA, wqkv, qkv_b, bufB, nullptr, MTOT, 3 * EMBED, EMBED);

    // windowed attention -> bufA
    attn_kernel<<<4096, 256, 0, stream>>>(bufB, rpb, bufA);

    // x2 = x + roll(attn @ proj_w^T + proj_b, +SHIFT)
    gemm256<1><<<dim3(512), 512, 0, stream>>>(bufA, wproj, proj_b, out, x, MTOT, EMBED, EMBED);

    // h2 = LN2(x2)
    ln_kernel<<<8192, 256, 0, stream>>>(out, n2w, n2b, bufA, 0);

    // MLP chunked (2 x 16384 rows)
    for (int c = 0; c < 2; ++c) {
        const size_t r0 = (size_t)c * 16384;
        gemm256<2><<<dim3(1024), 512, 0, stream>>>(bufA + r0 * EMBED, wm1, b1, bufB, nullptr,
                                                   16384, 4 * EMBED, EMBED);
        gemm256<3><<<dim3(256), 512, 0, stream>>>(bufB, wm2, b2, out + r0 * EMBED, nullptr,
                                                  16384, EMBED, 4 * EMBED);
    }
}